// Round 8
// baseline (205.880 us; speedup 1.0000x reference)
//
#include <hip/hip_runtime.h>
#include <math.h>

namespace {
constexpr int B    = 4;
constexpr int N    = 8192;
constexpr int P    = 2048;
constexpr int C    = 128;
constexpr int COUT = 256;
constexpr int NS   = 32;
constexpr int BP   = B * P;     // 8192
constexpr int GRP  = 8;         // bp per block (1 bp per group)
constexpr int NBLK = BP / GRP;  // 1024 blocks

// ---- workspace layout (bytes, all 256-aligned) ----
constexpr size_t OFF_FEATT = 0;                          // B*N*C bf16    = 8388608
constexpr size_t OFF_WSWZ  = 8388608;                    // 40960 bf16    = 81920
constexpr size_t OFF_SSLOT = 8470528;                    // 8*6 f64       = 384 (pad 512)
constexpr size_t OFF_SUMS  = 8471040;                    // 512 f32       = 2048 (pad 4096)
constexpr size_t OFF_IDX   = 8475136;                    // 8192*32 i32   = 1048576
constexpr size_t OFF_GX    = 9523712;                    // 8192*32 u64   = 2097152
constexpr size_t OFF_YMAX  = 11620864;                   // 8192*256 f32  = 8388608
constexpr size_t WS_NEED   = 20009472;                   // ~19.1 MB
} // namespace

typedef short bf16x8 __attribute__((ext_vector_type(8)));
typedef float f32x4  __attribute__((ext_vector_type(4)));

__device__ inline unsigned short f2bf(float f) {
    unsigned u = __float_as_uint(f);
    unsigned r = u + 0x7fffu + ((u >> 16) & 1u);
    return (unsigned short)(r >> 16);
}

// ============ R13 ============
// R8/R9/R12 invariance (2/CU, 4/CU-spilled, 3/CU-nospill all ~same total) says
// neither occupancy nor spill binds k_mlp: the invariant is the barrier-lockstep
// 8-group loop (each __syncthreads drains vmcnt(0) for all 4 waves -> any gather
// stall serializes the block; ~600cyc issue vs ~12k cyc/group wall). R13 removes
// the barrier AND the LDS: 1 bp per group; each wave gathers its own A-frags
// directly to VGPRs (8 dwordx4/group; 4 waves hit same lines -> L1). idx
// prefetched 2 groups ahead, ag/gx 1 group ahead, static parity dbuf (full
// unroll). Zero LDS, zero syncthreads -> independent wave streams.

// ---------------- K_A: shift BN partial stats (8 blocks) + zero sums ----------------
__global__ __launch_bounds__(256) void k_prep(const float* __restrict__ ffps,
                                              const float* __restrict__ wsh,
                                              double* __restrict__ sslot,
                                              float* __restrict__ sums) {
#pragma clang fp contract(off)
    int blk = blockIdx.x, t = threadIdx.x;
    if (blk == 8) {
        ((f32x4*)sums)[t & 127] = (f32x4){0.f, 0.f, 0.f, 0.f};  // 512 f32
        return;
    }
    __shared__ double red[6][256];
    double w[9];
#pragma unroll
    for (int i = 0; i < 9; i++) w[i] = (double)wsh[i];
    double s[3] = {0, 0, 0}, sq[3] = {0, 0, 0};
#pragma unroll
    for (int i = 0; i < 4; i++) {
        int p = blk * 1024 + t + 256 * i;
        double f0 = (double)ffps[p * 3 + 0];
        double f1 = (double)ffps[p * 3 + 1];
        double f2 = (double)ffps[p * 3 + 2];
#pragma unroll
        for (int o = 0; o < 3; o++) {
            double xo = (w[o * 3 + 0] * f0 + w[o * 3 + 1] * f1) + w[o * 3 + 2] * f2;
            s[o] += xo;
            sq[o] += xo * xo;
        }
    }
#pragma unroll
    for (int o = 0; o < 3; o++) { red[o][t] = s[o]; red[3 + o][t] = sq[o]; }
    for (int off = 128; off > 0; off >>= 1) {
        __syncthreads();
        if (t < off) {
#pragma unroll
            for (int j = 0; j < 6; j++) red[j][t] += red[j][t + off];
        }
    }
    __syncthreads();
    if (t < 6) sslot[blk * 6 + t] = red[t][0];
}

// ---------------- K_B: fused front — ballq (2048) || transpose (2048) || wswz (160) ----
__global__ __launch_bounds__(256) void k_front(const float* __restrict__ ffps,
                                               const float* __restrict__ bbxyz,
                                               const float* __restrict__ feat,
                                               const float* __restrict__ wsh,
                                               const float* __restrict__ gsh,
                                               const float* __restrict__ bsh,
                                               const float* __restrict__ wml,
                                               const double* __restrict__ sslot,
                                               unsigned short* __restrict__ featT,
                                               unsigned short* __restrict__ wswz,
                                               int* __restrict__ idxo,
                                               uint2* __restrict__ gxo) {
#pragma clang fp contract(off)
    int blk = blockIdx.x, t = threadIdx.x;
    if (blk >= 2048) {
        int rb = blk - 2048;
        if (rb < 2048) {
            // ---- transpose role: feat (B,C,N) f32 -> featT (B,N,C) bf16 ----
            __shared__ float tile[64][33];
            int tx = t & 31, ty = t >> 5;
            int n0 = (rb & 255) * 32, c0 = ((rb >> 8) & 1) * 64, b = rb >> 9;
            const float* src = feat + ((size_t)b * C + c0) * N + n0;
#pragma unroll
            for (int j = 0; j < 8; j++) tile[ty + 8 * j][tx] = src[(size_t)(ty + 8 * j) * N + tx];
            __syncthreads();
            int n = t >> 3;
            int k8 = (t & 7) * 8;
            unsigned vv[4];
#pragma unroll
            for (int i = 0; i < 4; i++) {
                unsigned lo = f2bf(tile[k8 + 2 * i][n]);
                unsigned hi = f2bf(tile[k8 + 2 * i + 1][n]);
                vv[i] = lo | (hi << 16);
            }
            *(int4*)&featT[((size_t)b * N + n0 + n) * C + c0 + k8] =
                make_int4((int)vv[0], (int)vv[1], (int)vv[2], (int)vv[3]);
        } else {
            // ---- wswz role: swizzle w_mlp into MFMA B-fragment order ----
            // wswz[rt(16)][ks(5)][lane(64)][j(8)]; element = W[rt*16+(lane&15)][k'];
            // k' = ks*32+(lane>>4)*8+j; k 0..127 -> col 3+k; 128..130 -> col 0..2.
            int i = (rb - 2048) * 256 + t;             // < 40960
            int j = i & 7;
            int lane = (i >> 3) & 63;
            int rest = i >> 9;
            int ks = rest % 5, rt = rest / 5;
            int cout = rt * 16 + (lane & 15);
            int k = ks * 32 + (lane >> 4) * 8 + j;
            float v = 0.f;
            if (k < 128) v = wml[cout * 131 + 3 + k];
            else if (k < 131) v = wml[cout * 131 + (k - 128)];
            wswz[i] = f2bf(v);
        }
        return;
    }

    // ---- ballq role ----
    __shared__ double spar[6];
    if (t < 6) {
        double a = 0.0;
        for (int r = 0; r < 8; r++) a += sslot[r * 6 + t];
        spar[t] = a;
    }
    __syncthreads();
    int wv = t >> 6, lane = t & 63;
    int q = blk * 4 + wv;                          // bp index
    int b = q >> 11;                               // P = 2048
    double f0 = (double)ffps[q * 3 + 0];
    double f1 = (double)ffps[q * 3 + 1];
    double f2 = (double)ffps[q * 3 + 2];
    double qd[3];
#pragma unroll
    for (int o = 0; o < 3; o++) {
        double m  = spar[o] * (1.0 / 8192.0);      // pow2: exact, == /BP
        double v  = spar[3 + o] * (1.0 / 8192.0) - m * m;
        double is = 1.0 / sqrt(v + 1e-5);
        double x  = ((double)wsh[o * 3 + 0] * f0 + (double)wsh[o * 3 + 1] * f1) +
                    (double)wsh[o * 3 + 2] * f2;
        double y  = ((x - m) * is) * (double)gsh[o] + (double)bsh[o];
        qd[o] = (y > 0.0) ? y : 0.0;
    }
    double qx = qd[0], qy = qd[1], qz = qd[2];
    float cfx = (float)qx, cfy = (float)qy, cfz = (float)qz;
    const float* base = bbxyz + (size_t)b * N * 3;
    const double R2 = 0.8 * 0.8;
    const float R2F = 0.64f;
    // early-out: ball cannot intersect [-1,1]^3 -> zero neighbors, pad idx 0
    {
        double ex = fmax(fmax(qx - 1.0, -1.0 - qx), 0.0);
        double ey = fmax(fmax(qy - 1.0, -1.0 - qy), 0.0);
        double ez = fmax(fmax(qz - 1.0, -1.0 - qz), 0.0);
        if (ex * ex + ey * ey + ez * ez >= R2) {
            if (lane < NS) {
                idxo[q * NS + lane] = 0;
                float rx = base[0] - cfx, ry = base[1] - cfy, rz = base[2] - cfz;
                unsigned u01 = (unsigned)f2bf(rx) | ((unsigned)f2bf(ry) << 16);
                gxo[q * NS + lane] = make_uint2(u01, (unsigned)f2bf(rz));
            }
            return;
        }
    }
    int found = 0, firstn = -1;

    float X0[8], Y0[8], Z0[8], X1[8], Y1[8], Z1[8], X2[8], Y2[8], Z2[8];

    auto loadb = [&](float (&XX)[8], float (&YY)[8], float (&ZZ)[8], int it) {
#pragma unroll
        for (int j = 0; j < 8; j++) {
            int n = it * 512 + j * 64 + lane;
            XX[j] = base[n * 3 + 0];
            YY[j] = base[n * 3 + 1];
            ZZ[j] = base[n * 3 + 2];
        }
    };
    auto proc = [&](float (&XX)[8], float (&YY)[8], float (&ZZ)[8], int it) {
#pragma clang fp contract(off)
#pragma unroll
        for (int j = 0; j < 8; j++) {
            int n = it * 512 + j * 64 + lane;
            float dxf = cfx - XX[j];
            float dyf = cfy - YY[j];
            float dzf = cfz - ZZ[j];
            float d2f = (dxf * dxf + dyf * dyf) + dzf * dzf;
            bool within;
            if (__builtin_expect(fabsf(d2f - R2F) < 1e-4f, 0)) {
                // borderline: exact original f64 op order decides
                double dx = qx - (double)XX[j];
                double dy = qy - (double)YY[j];
                double dz = qz - (double)ZZ[j];
                within = ((dx * dx + dy * dy) + dz * dz) < R2;
            } else {
                within = d2f < R2F;
            }
            unsigned long long mask = __ballot(within);
            if (firstn < 0 && mask != 0ull) firstn = (n - lane) + (__ffsll(mask) - 1);
            if (within) {
                int rank = found + __popcll(mask & ((1ull << lane) - 1ull));
                if (rank < NS) {
                    idxo[q * NS + rank] = n;
                    float rx = XX[j] - cfx, ry = YY[j] - cfy, rz = ZZ[j] - cfz;
                    unsigned u01 = (unsigned)f2bf(rx) | ((unsigned)f2bf(ry) << 16);
                    gxo[q * NS + rank] = make_uint2(u01, (unsigned)f2bf(rz));
                }
            }
            found += __popcll(mask);
        }
    };

    loadb(X0, Y0, Z0, 0);
    loadb(X1, Y1, Z1, 1);
    loadb(X2, Y2, Z2, 2);

    for (int itb = 0; itb < 16; itb += 3) {        // 512 pts/iter; N/512 = 16
        proc(X0, Y0, Z0, itb);
        if (found >= NS) break;
        loadb(X0, Y0, Z0, (itb + 3 < 16) ? itb + 3 : 0);
        if (itb + 1 >= 16) break;
        proc(X1, Y1, Z1, itb + 1);
        if (found >= NS) break;
        loadb(X1, Y1, Z1, (itb + 4 < 16) ? itb + 4 : 0);
        if (itb + 2 >= 16) break;
        proc(X2, Y2, Z2, itb + 2);
        if (found >= NS) break;
        loadb(X2, Y2, Z2, (itb + 5 < 16) ? itb + 5 : 0);
    }
    if (found < NS) {
        int padv = (found == 0) ? 0 : firstn;
        if (lane >= found && lane < NS) {
            idxo[q * NS + lane] = padv;
            float rx = base[padv * 3 + 0] - cfx;
            float ry = base[padv * 3 + 1] - cfy;
            float rz = base[padv * 3 + 2] - cfz;
            unsigned u01 = (unsigned)f2bf(rx) | ((unsigned)f2bf(ry) << 16);
            gxo[q * NS + lane] = make_uint2(u01, (unsigned)f2bf(rz));
        }
    }
}

// ---------------- K_C: MFMA 1x1 conv — barrier-free, LDS-free, reg-gather ----------
// Block = 4 waves, GRP=8 bp sequential, 1 bp per group. Wave w computes couts
// w*64..w*64+63 (4 nt). A-frags gathered per-lane to VGPRs (8 dwordx4/group;
// 4 waves share cache lines). Pipeline: idx 2 groups ahead into nreg[parity],
// ag/gx 1 group ahead into agb/gxv[parity]; full unroll keeps indices static.
// ~216 VGPR -> launch_bounds(256,2), no spill, no LDS, no __syncthreads.
__global__ __launch_bounds__(256, 2) void k_mlp_mfma(
        const unsigned short* __restrict__ featT,
        const unsigned short* __restrict__ wswz,
        const int* __restrict__ idx,
        const uint2* __restrict__ gxyz,
        float* __restrict__ ymax,
        float* __restrict__ sums) {
    int t = threadIdx.x, lane = t & 63, w = t >> 6;
    int q = lane >> 4, c16 = lane & 15;
    int blk = blockIdx.x;
    int bp0 = blk * GRP;
    const bf16x8* wp = (const bf16x8*)wswz;
    size_t fb = (size_t)(bp0 >> 11) * N * C;       // batch base (8 | 2048: const/block)
    int colo = q * 8;                              // this lane's column offset (bf16)

    // ---- W fragments resident: wave w's 4 cout-tiles ----
    bf16x8 wreg[5][4];
#pragma unroll
    for (int ks = 0; ks < 5; ks++)
#pragma unroll
        for (int nt = 0; nt < 4; nt++)
            wreg[ks][nt] = wp[((w * 4 + nt) * 5 + ks) * 64 + lane];

    // ---- pipeline state (static parity indexing) ----
    int nreg[2][2];           // [parity][mt]: rows for group with that parity
    bf16x8 agb[2][2][4];      // [parity][mt][ks]: A-frags
    uint2 gxv[2][2];          // [parity][mt]: packed recentered xyz (q==0 lanes)

    // prologue: rows(0), rows(1); ag/gx for group 0
#pragma unroll
    for (int mt = 0; mt < 2; mt++) {
        nreg[0][mt] = idx[(bp0 + 0) * NS + mt * 16 + c16] & (N - 1);
        nreg[1][mt] = idx[(bp0 + 1) * NS + mt * 16 + c16] & (N - 1);
    }
#pragma unroll
    for (int mt = 0; mt < 2; mt++) {
#pragma unroll
        for (int ks = 0; ks < 4; ks++)
            agb[0][mt][ks] = *(const bf16x8*)&featT[fb + (size_t)nreg[0][mt] * C + ks * 32 + colo];
        gxv[0][mt] = gxyz[(bp0 + 0) * NS + mt * 16 + c16];
    }

    float smA[4] = {0.f, 0.f, 0.f, 0.f}, sqA[4] = {0.f, 0.f, 0.f, 0.f};

#pragma unroll
    for (int g = 0; g < GRP; g++) {
        const int cur = g & 1, nxt = cur ^ 1;
        int bp = bp0 + g;
        // prefetch rows for group g+2 into nreg[cur] (its rows(g) already consumed)
        if (g + 2 < GRP) {
#pragma unroll
            for (int mt = 0; mt < 2; mt++)
                nreg[cur][mt] = idx[(bp + 2) * NS + mt * 16 + c16] & (N - 1);
        }
        // prefetch A-frags + gx for group g+1 (rows in nreg[nxt], loaded last iter)
        if (g + 1 < GRP) {
#pragma unroll
            for (int mt = 0; mt < 2; mt++) {
#pragma unroll
                for (int ks = 0; ks < 4; ks++)
                    agb[nxt][mt][ks] =
                        *(const bf16x8*)&featT[fb + (size_t)nreg[nxt][mt] * C + ks * 32 + colo];
                gxv[nxt][mt] = gxyz[(bp + 1) * NS + mt * 16 + c16];
            }
        }

        // ---- compute group g from registers ----
        f32x4 acc[2][4];
#pragma unroll
        for (int mt = 0; mt < 2; mt++)
#pragma unroll
            for (int nt = 0; nt < 4; nt++) acc[mt][nt] = (f32x4){0.f, 0.f, 0.f, 0.f};

#pragma unroll
        for (int ks = 0; ks < 4; ks++)
#pragma unroll
            for (int nt = 0; nt < 4; nt++)
#pragma unroll
                for (int mt = 0; mt < 2; mt++)
                    acc[mt][nt] = __builtin_amdgcn_mfma_f32_16x16x32_bf16(
                        agb[cur][mt][ks], wreg[ks][nt], acc[mt][nt], 0, 0, 0);
        {   // ks = 4: xyz A-frags (q==0 lanes carry recentered xyz, else 0)
            bf16x8 agx[2];
#pragma unroll
            for (int mt = 0; mt < 2; mt++) {
                union { int4 i; bf16x8 h; } u;
                u.i = make_int4(q == 0 ? (int)gxv[cur][mt].x : 0,
                                q == 0 ? (int)gxv[cur][mt].y : 0, 0, 0);
                agx[mt] = u.h;
            }
#pragma unroll
            for (int nt = 0; nt < 4; nt++)
#pragma unroll
                for (int mt = 0; mt < 2; mt++)
                    acc[mt][nt] = __builtin_amdgcn_mfma_f32_16x16x32_bf16(
                        agx[mt], wreg[4][nt], acc[mt][nt], 0, 0, 0);
        }

        // ---- epilogue: max over 32 samples (2 mt x 4 regs x shfl over q) ----
#pragma unroll
        for (int nt = 0; nt < 4; nt++) {
            f32x4 a = acc[0][nt], c = acc[1][nt];
            float mx = fmaxf(fmaxf(fmaxf(a[0], a[1]), fmaxf(a[2], a[3])),
                             fmaxf(fmaxf(c[0], c[1]), fmaxf(c[2], c[3])));
            smA[nt] += ((a[0] + a[1]) + (a[2] + a[3])) + ((c[0] + c[1]) + (c[2] + c[3]));
            sqA[nt] += ((a[0] * a[0] + a[1] * a[1]) + (a[2] * a[2] + a[3] * a[3])) +
                       ((c[0] * c[0] + c[1] * c[1]) + (c[2] * c[2] + c[3] * c[3]));
            mx = fmaxf(mx, __shfl_xor(mx, 16, 64));
            mx = fmaxf(mx, __shfl_xor(mx, 32, 64));
            if (q == 0)
                ymax[(size_t)bp * COUT + w * 64 + nt * 16 + c16] = mx;
        }
    }

    // ---- per-channel sums -> global atomics (once per block) ----
#pragma unroll
    for (int nt = 0; nt < 4; nt++) {
        float sm = smA[nt], sq = sqA[nt];
        sm += __shfl_xor(sm, 16, 64);
        sm += __shfl_xor(sm, 32, 64);
        sq += __shfl_xor(sq, 16, 64);
        sq += __shfl_xor(sq, 32, 64);
        if (q == 0) {
            int cout = w * 64 + nt * 16 + c16;
            atomicAdd(&sums[cout], sm);
            atomicAdd(&sums[256 + cout], sq);
        }
    }
}

// ---------------- K_D: BN params from sums, then relu(a*ymax+b), float4 ----------
__global__ __launch_bounds__(256) void k_final(const float* __restrict__ ymax,
                                               const float* __restrict__ sums,
                                               const float* __restrict__ gam,
                                               const float* __restrict__ bet,
                                               float* __restrict__ out) {
    __shared__ float sa[256], sb[256];
    int t = threadIdx.x;
    {
        double sm = (double)sums[t], sq = (double)sums[256 + t];
        double mean = sm * (1.0 / 262144.0);       // BP*NS, pow2
        double var = sq * (1.0 / 262144.0) - mean * mean;
        double a = (double)gam[t] / sqrt(var + 1e-5);
        sa[t] = (float)a;
        sb[t] = (float)((double)bet[t] - mean * a);
    }
    __syncthreads();
    int i = blockIdx.x * 256 + t;                  // float4 index, < BP*COUT/4
    int c0 = (t & 63) * 4;                         // (i&63)==(t&63) since 256%64==0
    f32x4 y = *(const f32x4*)&ymax[(size_t)i * 4];
    f32x4 r;
#pragma unroll
    for (int j = 0; j < 4; j++) r[j] = fmaxf(sa[c0 + j] * y[j] + sb[c0 + j], 0.f);
    *(f32x4*)&out[(size_t)i * 4] = r;
}

extern "C" void kernel_launch(void* const* d_in, const int* in_sizes, int n_in,
                              void* d_out, int out_size, void* d_ws, size_t ws_size,
                              hipStream_t stream) {
    const float* ffps  = (const float*)d_in[0];
    const float* bbxyz = (const float*)d_in[1];
    const float* feat  = (const float*)d_in[2];
    const float* wsh   = (const float*)d_in[3];
    const float* gsh   = (const float*)d_in[4];
    const float* bsh   = (const float*)d_in[5];
    const float* wml   = (const float*)d_in[6];
    const float* gml   = (const float*)d_in[7];
    const float* bml   = (const float*)d_in[8];
    float* out = (float*)d_out;
    char* ws = (char*)d_ws;
    if (ws_size < WS_NEED) return;

    unsigned short* featT = (unsigned short*)(ws + OFF_FEATT);
    unsigned short* wswz  = (unsigned short*)(ws + OFF_WSWZ);
    double*         sslot = (double*)(ws + OFF_SSLOT);
    float*          sums  = (float*)(ws + OFF_SUMS);
    int*            idx   = (int*)(ws + OFF_IDX);
    uint2*          gx    = (uint2*)(ws + OFF_GX);
    float*          ymax  = (float*)(ws + OFF_YMAX);

    k_prep<<<dim3(9), dim3(256), 0, stream>>>(ffps, wsh, sslot, sums);
    k_front<<<dim3(2048 + 2048 + 160), dim3(256), 0, stream>>>(
        ffps, bbxyz, feat, wsh, gsh, bsh, wml, sslot, featT, wswz, idx, gx);
    k_mlp_mfma<<<dim3(NBLK), dim3(256), 0, stream>>>(featT, wswz, idx, gx, ymax, sums);
    k_final<<<dim3(BP * COUT / 1024), dim3(256), 0, stream>>>(ymax, sums, gml, bml, out);
}

// Round 9
// 172.340 us; speedup vs baseline: 1.1946x; 1.1946x over previous
//
#include <hip/hip_runtime.h>
#include <math.h>

namespace {
constexpr int B    = 4;
constexpr int N    = 8192;
constexpr int P    = 2048;
constexpr int C    = 128;
constexpr int COUT = 256;
constexpr int NS   = 32;
constexpr int BP   = B * P;     // 8192
constexpr int GRP  = 8;         // bp per block (1 bp per group)
constexpr int NBLK = BP / GRP;  // 1024 blocks

// ---- workspace layout (bytes, all 256-aligned) ----
constexpr size_t OFF_FEATT = 0;                          // B*N*C bf16    = 8388608
constexpr size_t OFF_WSWZ  = 8388608;                    // 40960 bf16    = 81920
constexpr size_t OFF_SSLOT = 8470528;                    // 8*6 f64       = 384 (pad 512)
constexpr size_t OFF_SUMS  = 8471040;                    // 512 f32       = 2048 (pad 4096)
constexpr size_t OFF_IDX   = 8475136;                    // 8192*32 i32   = 1048576
constexpr size_t OFF_GX    = 9523712;                    // 8192*32 u64   = 2097152
constexpr size_t OFF_YMAX  = 11620864;                   // 8192*256 f32  = 8388608
constexpr size_t WS_NEED   = 20009472;                   // ~19.1 MB
} // namespace

typedef short bf16x8 __attribute__((ext_vector_type(8)));
typedef float f32x4  __attribute__((ext_vector_type(4)));

__device__ inline unsigned short f2bf(float f) {
    unsigned u = __float_as_uint(f);
    unsigned r = u + 0x7fffu + ((u >> 16) & 1u);
    return (unsigned short)(r >> 16);
}

// ============ R14 ============
// R13's barrier-free k_mlp was right in concept but died on rule #20: the
// parity-indexed agb[cur] needed full unroll of the 8-group loop; compiler
// didn't unroll -> runtime index -> 130MB/disp scratch (VGPR 128, 90us).
// R14: same dataflow, spill-proof by construction — NAMED buffers (nA/agA/gxA
// for even groups, nB/agB/gxB for odd), loop over 4 group-pairs; all register
// arrays statically indexed no matter what the scheduler does. ~200 VGPR under
// the (256,2) 256-cap. Zero LDS, zero __syncthreads: per-wave independent
// gather streams, each drained under ~40 MFMAs of compute.

// ---------------- K_A: shift BN partial stats (8 blocks) + zero sums ----------------
__global__ __launch_bounds__(256) void k_prep(const float* __restrict__ ffps,
                                              const float* __restrict__ wsh,
                                              double* __restrict__ sslot,
                                              float* __restrict__ sums) {
#pragma clang fp contract(off)
    int blk = blockIdx.x, t = threadIdx.x;
    if (blk == 8) {
        ((f32x4*)sums)[t & 127] = (f32x4){0.f, 0.f, 0.f, 0.f};  // 512 f32
        return;
    }
    __shared__ double red[6][256];
    double w[9];
#pragma unroll
    for (int i = 0; i < 9; i++) w[i] = (double)wsh[i];
    double s[3] = {0, 0, 0}, sq[3] = {0, 0, 0};
#pragma unroll
    for (int i = 0; i < 4; i++) {
        int p = blk * 1024 + t + 256 * i;
        double f0 = (double)ffps[p * 3 + 0];
        double f1 = (double)ffps[p * 3 + 1];
        double f2 = (double)ffps[p * 3 + 2];
#pragma unroll
        for (int o = 0; o < 3; o++) {
            double xo = (w[o * 3 + 0] * f0 + w[o * 3 + 1] * f1) + w[o * 3 + 2] * f2;
            s[o] += xo;
            sq[o] += xo * xo;
        }
    }
#pragma unroll
    for (int o = 0; o < 3; o++) { red[o][t] = s[o]; red[3 + o][t] = sq[o]; }
    for (int off = 128; off > 0; off >>= 1) {
        __syncthreads();
        if (t < off) {
#pragma unroll
            for (int j = 0; j < 6; j++) red[j][t] += red[j][t + off];
        }
    }
    __syncthreads();
    if (t < 6) sslot[blk * 6 + t] = red[t][0];
}

// ---------------- K_B: fused front — ballq (2048) || transpose (2048) || wswz (160) ----
__global__ __launch_bounds__(256) void k_front(const float* __restrict__ ffps,
                                               const float* __restrict__ bbxyz,
                                               const float* __restrict__ feat,
                                               const float* __restrict__ wsh,
                                               const float* __restrict__ gsh,
                                               const float* __restrict__ bsh,
                                               const float* __restrict__ wml,
                                               const double* __restrict__ sslot,
                                               unsigned short* __restrict__ featT,
                                               unsigned short* __restrict__ wswz,
                                               int* __restrict__ idxo,
                                               uint2* __restrict__ gxo) {
#pragma clang fp contract(off)
    int blk = blockIdx.x, t = threadIdx.x;
    if (blk >= 2048) {
        int rb = blk - 2048;
        if (rb < 2048) {
            // ---- transpose role: feat (B,C,N) f32 -> featT (B,N,C) bf16 ----
            __shared__ float tile[64][33];
            int tx = t & 31, ty = t >> 5;
            int n0 = (rb & 255) * 32, c0 = ((rb >> 8) & 1) * 64, b = rb >> 9;
            const float* src = feat + ((size_t)b * C + c0) * N + n0;
#pragma unroll
            for (int j = 0; j < 8; j++) tile[ty + 8 * j][tx] = src[(size_t)(ty + 8 * j) * N + tx];
            __syncthreads();
            int n = t >> 3;
            int k8 = (t & 7) * 8;
            unsigned vv[4];
#pragma unroll
            for (int i = 0; i < 4; i++) {
                unsigned lo = f2bf(tile[k8 + 2 * i][n]);
                unsigned hi = f2bf(tile[k8 + 2 * i + 1][n]);
                vv[i] = lo | (hi << 16);
            }
            *(int4*)&featT[((size_t)b * N + n0 + n) * C + c0 + k8] =
                make_int4((int)vv[0], (int)vv[1], (int)vv[2], (int)vv[3]);
        } else {
            // ---- wswz role: swizzle w_mlp into MFMA B-fragment order ----
            // wswz[rt(16)][ks(5)][lane(64)][j(8)]; element = W[rt*16+(lane&15)][k'];
            // k' = ks*32+(lane>>4)*8+j; k 0..127 -> col 3+k; 128..130 -> col 0..2.
            int i = (rb - 2048) * 256 + t;             // < 40960
            int j = i & 7;
            int lane = (i >> 3) & 63;
            int rest = i >> 9;
            int ks = rest % 5, rt = rest / 5;
            int cout = rt * 16 + (lane & 15);
            int k = ks * 32 + (lane >> 4) * 8 + j;
            float v = 0.f;
            if (k < 128) v = wml[cout * 131 + 3 + k];
            else if (k < 131) v = wml[cout * 131 + (k - 128)];
            wswz[i] = f2bf(v);
        }
        return;
    }

    // ---- ballq role ----
    __shared__ double spar[6];
    if (t < 6) {
        double a = 0.0;
        for (int r = 0; r < 8; r++) a += sslot[r * 6 + t];
        spar[t] = a;
    }
    __syncthreads();
    int wv = t >> 6, lane = t & 63;
    int q = blk * 4 + wv;                          // bp index
    int b = q >> 11;                               // P = 2048
    double f0 = (double)ffps[q * 3 + 0];
    double f1 = (double)ffps[q * 3 + 1];
    double f2 = (double)ffps[q * 3 + 2];
    double qd[3];
#pragma unroll
    for (int o = 0; o < 3; o++) {
        double m  = spar[o] * (1.0 / 8192.0);      // pow2: exact, == /BP
        double v  = spar[3 + o] * (1.0 / 8192.0) - m * m;
        double is = 1.0 / sqrt(v + 1e-5);
        double x  = ((double)wsh[o * 3 + 0] * f0 + (double)wsh[o * 3 + 1] * f1) +
                    (double)wsh[o * 3 + 2] * f2;
        double y  = ((x - m) * is) * (double)gsh[o] + (double)bsh[o];
        qd[o] = (y > 0.0) ? y : 0.0;
    }
    double qx = qd[0], qy = qd[1], qz = qd[2];
    float cfx = (float)qx, cfy = (float)qy, cfz = (float)qz;
    const float* base = bbxyz + (size_t)b * N * 3;
    const double R2 = 0.8 * 0.8;
    const float R2F = 0.64f;
    // early-out: ball cannot intersect [-1,1]^3 -> zero neighbors, pad idx 0
    {
        double ex = fmax(fmax(qx - 1.0, -1.0 - qx), 0.0);
        double ey = fmax(fmax(qy - 1.0, -1.0 - qy), 0.0);
        double ez = fmax(fmax(qz - 1.0, -1.0 - qz), 0.0);
        if (ex * ex + ey * ey + ez * ez >= R2) {
            if (lane < NS) {
                idxo[q * NS + lane] = 0;
                float rx = base[0] - cfx, ry = base[1] - cfy, rz = base[2] - cfz;
                unsigned u01 = (unsigned)f2bf(rx) | ((unsigned)f2bf(ry) << 16);
                gxo[q * NS + lane] = make_uint2(u01, (unsigned)f2bf(rz));
            }
            return;
        }
    }
    int found = 0, firstn = -1;

    float X0[8], Y0[8], Z0[8], X1[8], Y1[8], Z1[8], X2[8], Y2[8], Z2[8];

    auto loadb = [&](float (&XX)[8], float (&YY)[8], float (&ZZ)[8], int it) {
#pragma unroll
        for (int j = 0; j < 8; j++) {
            int n = it * 512 + j * 64 + lane;
            XX[j] = base[n * 3 + 0];
            YY[j] = base[n * 3 + 1];
            ZZ[j] = base[n * 3 + 2];
        }
    };
    auto proc = [&](float (&XX)[8], float (&YY)[8], float (&ZZ)[8], int it) {
#pragma clang fp contract(off)
#pragma unroll
        for (int j = 0; j < 8; j++) {
            int n = it * 512 + j * 64 + lane;
            float dxf = cfx - XX[j];
            float dyf = cfy - YY[j];
            float dzf = cfz - ZZ[j];
            float d2f = (dxf * dxf + dyf * dyf) + dzf * dzf;
            bool within;
            if (__builtin_expect(fabsf(d2f - R2F) < 1e-4f, 0)) {
                // borderline: exact original f64 op order decides
                double dx = qx - (double)XX[j];
                double dy = qy - (double)YY[j];
                double dz = qz - (double)ZZ[j];
                within = ((dx * dx + dy * dy) + dz * dz) < R2;
            } else {
                within = d2f < R2F;
            }
            unsigned long long mask = __ballot(within);
            if (firstn < 0 && mask != 0ull) firstn = (n - lane) + (__ffsll(mask) - 1);
            if (within) {
                int rank = found + __popcll(mask & ((1ull << lane) - 1ull));
                if (rank < NS) {
                    idxo[q * NS + rank] = n;
                    float rx = XX[j] - cfx, ry = YY[j] - cfy, rz = ZZ[j] - cfz;
                    unsigned u01 = (unsigned)f2bf(rx) | ((unsigned)f2bf(ry) << 16);
                    gxo[q * NS + rank] = make_uint2(u01, (unsigned)f2bf(rz));
                }
            }
            found += __popcll(mask);
        }
    };

    loadb(X0, Y0, Z0, 0);
    loadb(X1, Y1, Z1, 1);
    loadb(X2, Y2, Z2, 2);

    for (int itb = 0; itb < 16; itb += 3) {        // 512 pts/iter; N/512 = 16
        proc(X0, Y0, Z0, itb);
        if (found >= NS) break;
        loadb(X0, Y0, Z0, (itb + 3 < 16) ? itb + 3 : 0);
        if (itb + 1 >= 16) break;
        proc(X1, Y1, Z1, itb + 1);
        if (found >= NS) break;
        loadb(X1, Y1, Z1, (itb + 4 < 16) ? itb + 4 : 0);
        if (itb + 2 >= 16) break;
        proc(X2, Y2, Z2, itb + 2);
        if (found >= NS) break;
        loadb(X2, Y2, Z2, (itb + 5 < 16) ? itb + 5 : 0);
    }
    if (found < NS) {
        int padv = (found == 0) ? 0 : firstn;
        if (lane >= found && lane < NS) {
            idxo[q * NS + lane] = padv;
            float rx = base[padv * 3 + 0] - cfx;
            float ry = base[padv * 3 + 1] - cfy;
            float rz = base[padv * 3 + 2] - cfz;
            unsigned u01 = (unsigned)f2bf(rx) | ((unsigned)f2bf(ry) << 16);
            gxo[q * NS + lane] = make_uint2(u01, (unsigned)f2bf(rz));
        }
    }
}

// ---------------- K_C: MFMA 1x1 conv — barrier-free reg-gather, NAMED dbuf ----------
// Block = 4 waves; GRP=8 bp sequential; wave w owns couts w*64..+63 (4 nt).
// A-frags per-lane direct from featT (lane c16 -> its sample row, col q*8+ks*32
// == the 16x16x32 A layout). Even/odd named buffers; all reg-array indices
// compile-time. Per iteration: load agB(odd) | nA(gE+2) | compute(even) |
// load agA(gE+2) | nB(gO+2) | compute(odd).
__global__ __launch_bounds__(256, 2) void k_mlp_mfma(
        const unsigned short* __restrict__ featT,
        const unsigned short* __restrict__ wswz,
        const int* __restrict__ idx,
        const uint2* __restrict__ gxyz,
        float* __restrict__ ymax,
        float* __restrict__ sums) {
    int t = threadIdx.x, lane = t & 63, w = t >> 6;
    int q = lane >> 4, c16 = lane & 15;
    int blk = blockIdx.x;
    int bp0 = blk * GRP;
    const bf16x8* wp = (const bf16x8*)wswz;
    size_t fb = (size_t)(bp0 >> 11) * N * C;       // batch base (8 | 2048: const/block)
    int colo = q * 8;                              // lane's column offset (bf16)

    // ---- W fragments resident: wave w's 4 cout-tiles ----
    bf16x8 wreg[5][4];
#pragma unroll
    for (int ks = 0; ks < 5; ks++)
#pragma unroll
        for (int nt = 0; nt < 4; nt++)
            wreg[ks][nt] = wp[((w * 4 + nt) * 5 + ks) * 64 + lane];

    float smA[4] = {0.f, 0.f, 0.f, 0.f}, sqA[4] = {0.f, 0.f, 0.f, 0.f};

    // ---- named pipeline buffers (NO parity indexing) ----
    int nA[2], nB[2];
    bf16x8 agA[2][4], agB[2][4];
    uint2 gxA[2], gxB[2];

    auto loadRows = [&](int (&nn)[2], int bp) {
#pragma unroll
        for (int mt = 0; mt < 2; mt++)
            nn[mt] = idx[bp * NS + mt * 16 + c16] & (N - 1);
    };
    auto loadFrags = [&](bf16x8 (&ag)[2][4], uint2 (&gx)[2], const int (&nn)[2], int bp) {
#pragma unroll
        for (int mt = 0; mt < 2; mt++) {
#pragma unroll
            for (int ks = 0; ks < 4; ks++)
                ag[mt][ks] = *(const bf16x8*)&featT[fb + (size_t)nn[mt] * C + ks * 32 + colo];
            gx[mt] = gxyz[bp * NS + mt * 16 + c16];
        }
    };
    auto compute = [&](int bp, const bf16x8 (&ag)[2][4], const uint2 (&gx)[2]) {
        f32x4 acc[2][4];
#pragma unroll
        for (int mt = 0; mt < 2; mt++)
#pragma unroll
            for (int nt = 0; nt < 4; nt++) acc[mt][nt] = (f32x4){0.f, 0.f, 0.f, 0.f};
#pragma unroll
        for (int ks = 0; ks < 4; ks++)
#pragma unroll
            for (int nt = 0; nt < 4; nt++)
#pragma unroll
                for (int mt = 0; mt < 2; mt++)
                    acc[mt][nt] = __builtin_amdgcn_mfma_f32_16x16x32_bf16(
                        ag[mt][ks], wreg[ks][nt], acc[mt][nt], 0, 0, 0);
        {   // ks = 4: xyz A-frags (q==0 lanes carry recentered xyz, else 0)
            bf16x8 agx[2];
#pragma unroll
            for (int mt = 0; mt < 2; mt++) {
                union { int4 i; bf16x8 h; } u;
                u.i = make_int4(q == 0 ? (int)gx[mt].x : 0,
                                q == 0 ? (int)gx[mt].y : 0, 0, 0);
                agx[mt] = u.h;
            }
#pragma unroll
            for (int nt = 0; nt < 4; nt++)
#pragma unroll
                for (int mt = 0; mt < 2; mt++)
                    acc[mt][nt] = __builtin_amdgcn_mfma_f32_16x16x32_bf16(
                        agx[mt], wreg[4][nt], acc[mt][nt], 0, 0, 0);
        }
        // epilogue: max over 32 samples (2 mt x 4 regs x shfl over q); sums accum
#pragma unroll
        for (int nt = 0; nt < 4; nt++) {
            f32x4 a = acc[0][nt], c = acc[1][nt];
            float mx = fmaxf(fmaxf(fmaxf(a[0], a[1]), fmaxf(a[2], a[3])),
                             fmaxf(fmaxf(c[0], c[1]), fmaxf(c[2], c[3])));
            smA[nt] += ((a[0] + a[1]) + (a[2] + a[3])) + ((c[0] + c[1]) + (c[2] + c[3]));
            sqA[nt] += ((a[0] * a[0] + a[1] * a[1]) + (a[2] * a[2] + a[3] * a[3])) +
                       ((c[0] * c[0] + c[1] * c[1]) + (c[2] * c[2] + c[3] * c[3]));
            mx = fmaxf(mx, __shfl_xor(mx, 16, 64));
            mx = fmaxf(mx, __shfl_xor(mx, 32, 64));
            if (q == 0)
                ymax[(size_t)bp * COUT + w * 64 + nt * 16 + c16] = mx;
        }
    };

    // prologue
    loadRows(nA, bp0 + 0);
    loadRows(nB, bp0 + 1);
    loadFrags(agA, gxA, nA, bp0 + 0);

    for (int gp = 0; gp < 4; gp++) {               // 2 groups per iteration
        int gE = 2 * gp, gO = gE + 1;
        loadFrags(agB, gxB, nB, bp0 + gO);         // odd frags (rows from last iter)
        if (gE + 2 < GRP) loadRows(nA, bp0 + gE + 2);
        compute(bp0 + gE, agA, gxA);               // covers agB + nA latency
        if (gE + 2 < GRP) loadFrags(agA, gxA, nA, bp0 + gE + 2);
        if (gO + 2 < GRP) loadRows(nB, bp0 + gO + 2);
        compute(bp0 + gO, agB, gxB);               // covers agA + nB latency
    }

    // ---- per-channel sums -> global atomics (once per block) ----
#pragma unroll
    for (int nt = 0; nt < 4; nt++) {
        float sm = smA[nt], sq = sqA[nt];
        sm += __shfl_xor(sm, 16, 64);
        sm += __shfl_xor(sm, 32, 64);
        sq += __shfl_xor(sq, 16, 64);
        sq += __shfl_xor(sq, 32, 64);
        if (q == 0) {
            int cout = w * 64 + nt * 16 + c16;
            atomicAdd(&sums[cout], sm);
            atomicAdd(&sums[256 + cout], sq);
        }
    }
}

// ---------------- K_D: BN params from sums, then relu(a*ymax+b), float4 ----------
__global__ __launch_bounds__(256) void k_final(const float* __restrict__ ymax,
                                               const float* __restrict__ sums,
                                               const float* __restrict__ gam,
                                               const float* __restrict__ bet,
                                               float* __restrict__ out) {
    __shared__ float sa[256], sb[256];
    int t = threadIdx.x;
    {
        double sm = (double)sums[t], sq = (double)sums[256 + t];
        double mean = sm * (1.0 / 262144.0);       // BP*NS, pow2
        double var = sq * (1.0 / 262144.0) - mean * mean;
        double a = (double)gam[t] / sqrt(var + 1e-5);
        sa[t] = (float)a;
        sb[t] = (float)((double)bet[t] - mean * a);
    }
    __syncthreads();
    int i = blockIdx.x * 256 + t;                  // float4 index, < BP*COUT/4
    int c0 = (t & 63) * 4;                         // (i&63)==(t&63) since 256%64==0
    f32x4 y = *(const f32x4*)&ymax[(size_t)i * 4];
    f32x4 r;
#pragma unroll
    for (int j = 0; j < 4; j++) r[j] = fmaxf(sa[c0 + j] * y[j] + sb[c0 + j], 0.f);
    *(f32x4*)&out[(size_t)i * 4] = r;
}

extern "C" void kernel_launch(void* const* d_in, const int* in_sizes, int n_in,
                              void* d_out, int out_size, void* d_ws, size_t ws_size,
                              hipStream_t stream) {
    const float* ffps  = (const float*)d_in[0];
    const float* bbxyz = (const float*)d_in[1];
    const float* feat  = (const float*)d_in[2];
    const float* wsh   = (const float*)d_in[3];
    const float* gsh   = (const float*)d_in[4];
    const float* bsh   = (const float*)d_in[5];
    const float* wml   = (const float*)d_in[6];
    const float* gml   = (const float*)d_in[7];
    const float* bml   = (const float*)d_in[8];
    float* out = (float*)d_out;
    char* ws = (char*)d_ws;
    if (ws_size < WS_NEED) return;

    unsigned short* featT = (unsigned short*)(ws + OFF_FEATT);
    unsigned short* wswz  = (unsigned short*)(ws + OFF_WSWZ);
    double*         sslot = (double*)(ws + OFF_SSLOT);
    float*          sums  = (float*)(ws + OFF_SUMS);
    int*            idx   = (int*)(ws + OFF_IDX);
    uint2*          gx    = (uint2*)(ws + OFF_GX);
    float*          ymax  = (float*)(ws + OFF_YMAX);

    k_prep<<<dim3(9), dim3(256), 0, stream>>>(ffps, wsh, sslot, sums);
    k_front<<<dim3(2048 + 2048 + 160), dim3(256), 0, stream>>>(
        ffps, bbxyz, feat, wsh, gsh, bsh, wml, sslot, featT, wswz, idx, gx);
    k_mlp_mfma<<<dim3(NBLK), dim3(256), 0, stream>>>(featT, wswz, idx, gx, ymax, sums);
    k_final<<<dim3(BP * COUT / 1024), dim3(256), 0, stream>>>(ymax, sums, gml, bml, out);
}